// Round 1
// baseline (49426.361 us; speedup 1.0000x reference)
//
#include <hip/hip_runtime.h>
#include <hip/hip_bf16.h>
#include <math.h>

#define B_   64
#define T_   256
#define DIN_ 512
#define H_   512
#define D_   1024
#define O_   1536
#define TB_  (T_*B_)
#define EPSf 1e-5f

// ---------------- fill: Hseq[t][b][d] = d<DIN ? x[b][t][d] : 0 ----------------
__global__ __launch_bounds__(256) void k_fill(const float* __restrict__ x,
                                              float* __restrict__ Hseq) {
    int g  = blockIdx.x * 256 + threadIdx.x;   // over TB_*D_/4
    int i4 = g * 4;
    int row = i4 / D_;          // t*B + b
    int d   = i4 % D_;
    int t = row / B_, b = row % B_;
    float4 v = make_float4(0.f, 0.f, 0.f, 0.f);
    if (d < DIN_) v = *(const float4*)&x[((size_t)b * T_ + t) * DIN_ + d];
    *(float4*)&Hseq[(size_t)i4] = v;
}

// ---------------- fp32 tiled GEMM: C[M,N] = A[M,K] @ W[K,N] ----------------
#define GBM 64
#define GBN 64
#define GBK 16
__global__ __launch_bounds__(256) void k_gemm(const float* __restrict__ A,
                                              const float* __restrict__ Wm,
                                              float* __restrict__ C,
                                              int M, int N, int K) {
    __shared__ float As[GBK][GBM];   // transposed tile: As[k][r]
    __shared__ float Bs[GBK][GBN];
    int tid = threadIdx.x;
    int tx = tid % 16, ty = tid / 16;
    int row0 = blockIdx.y * GBM, col0 = blockIdx.x * GBN;
    float acc[4][4] = {};
    int lr = tid % 64, lk = tid / 64;          // A load: row lr, k-quad lk
    int bk = tid / 16, bc4 = (tid % 16) * 4;   // B load: k-row bk, col-quad bc4
    for (int k0 = 0; k0 < K; k0 += GBK) {
        float4 av = *(const float4*)&A[(size_t)(row0 + lr) * K + k0 + lk * 4];
        As[lk * 4 + 0][lr] = av.x;
        As[lk * 4 + 1][lr] = av.y;
        As[lk * 4 + 2][lr] = av.z;
        As[lk * 4 + 3][lr] = av.w;
        float4 bv = *(const float4*)&Wm[(size_t)(k0 + bk) * N + col0 + bc4];
        *(float4*)&Bs[bk][bc4] = bv;
        __syncthreads();
#pragma unroll
        for (int kk = 0; kk < GBK; ++kk) {
            float4 a  = *(const float4*)&As[kk][ty * 4];
            float4 bb = *(const float4*)&Bs[kk][tx * 4];
            acc[0][0] += a.x * bb.x; acc[0][1] += a.x * bb.y; acc[0][2] += a.x * bb.z; acc[0][3] += a.x * bb.w;
            acc[1][0] += a.y * bb.x; acc[1][1] += a.y * bb.y; acc[1][2] += a.y * bb.z; acc[1][3] += a.y * bb.w;
            acc[2][0] += a.z * bb.x; acc[2][1] += a.z * bb.y; acc[2][2] += a.z * bb.z; acc[2][3] += a.z * bb.w;
            acc[3][0] += a.w * bb.x; acc[3][1] += a.w * bb.y; acc[3][2] += a.w * bb.z; acc[3][3] += a.w * bb.w;
        }
        __syncthreads();
    }
#pragma unroll
    for (int i = 0; i < 4; ++i) {
        float4 o = make_float4(acc[i][0], acc[i][1], acc[i][2], acc[i][3]);
        *(float4*)&C[(size_t)(row0 + ty * 4 + i) * N + col0 + tx * 4] = o;
    }
}

// ---------------- in-place row LayerNorm + bias: S := g*(S-m)/(std+eps)+be+bias ----
__global__ __launch_bounds__(256) void k_ln_bias(float* __restrict__ S,
                                                 const float* __restrict__ gamma,
                                                 const float* __restrict__ beta,
                                                 const float* __restrict__ bias) {
    size_t row = blockIdx.x;
    float v[6];
    float s = 0.f, s2 = 0.f;
#pragma unroll
    for (int j = 0; j < 6; ++j) {
        v[j] = S[row * O_ + j * 256 + threadIdx.x];
        s += v[j]; s2 += v[j] * v[j];
    }
    for (int off = 32; off; off >>= 1) { s += __shfl_down(s, off); s2 += __shfl_down(s2, off); }
    __shared__ float red[8];
    int wid = threadIdx.x / 64, lane = threadIdx.x % 64;
    if (lane == 0) { red[wid] = s; red[4 + wid] = s2; }
    __syncthreads();
    float ts = red[0] + red[1] + red[2] + red[3];
    float t2 = red[4] + red[5] + red[6] + red[7];
    float mean = ts * (1.f / O_);
    float var  = t2 * (1.f / O_) - mean * mean;
    float inv  = 1.f / (sqrtf(var + EPSf) + EPSf);
#pragma unroll
    for (int j = 0; j < 6; ++j) {
        int o = j * 256 + threadIdx.x;
        S[row * O_ + o] = gamma[o] * (v[j] - mean) * inv + beta[o] + bias[o];
    }
}

// ---------------- phase B step A: Y = h_tm1 @ U, plus per-row sum/sumsq ----------
// grid (O_/64, B_/16), block 256 (4 waves; wave rg owns rows rg*4..rg*4+3)
__global__ __launch_bounds__(256) void k_stepA(const float* __restrict__ h,
                                               const float* __restrict__ U,
                                               float* __restrict__ Y,
                                               float* __restrict__ stats,
                                               int t) {
    __shared__ float As[32][20];   // As[k][r], padded stride 20 (16B-aligned float4 rows)
    __shared__ float Bs[32][64];
    int tid = threadIdx.x;
    int col = tid % 64;
    int rg  = tid / 64;            // wave id 0..3
    int row0 = blockIdx.y * 16;
    int col0 = blockIdx.x * 64;
    float acc[4] = {0.f, 0.f, 0.f, 0.f};
    int ar = tid / 16, ak2 = (tid % 16) * 2;
    int bk = tid / 16, bc4 = (tid % 16) * 4;
    for (int k0 = 0; k0 < D_; k0 += 32) {
        float2 av = *(const float2*)&h[(size_t)(row0 + ar) * D_ + k0 + ak2];
        As[ak2][ar] = av.x;
        As[ak2 + 1][ar] = av.y;
#pragma unroll
        for (int u = 0; u < 2; ++u) {
            float4 bv = *(const float4*)&U[(size_t)(k0 + bk + u * 16) * O_ + col0 + bc4];
            *(float4*)&Bs[bk + u * 16][bc4] = bv;
        }
        __syncthreads();
#pragma unroll
        for (int kk = 0; kk < 32; ++kk) {
            float4 a4 = *(const float4*)&As[kk][rg * 4];   // broadcast within wave
            float bvv = Bs[kk][col];
            acc[0] += a4.x * bvv;
            acc[1] += a4.y * bvv;
            acc[2] += a4.z * bvv;
            acc[3] += a4.w * bvv;
        }
        __syncthreads();
    }
#pragma unroll
    for (int i = 0; i < 4; ++i)
        Y[(size_t)(row0 + rg * 4 + i) * O_ + col0 + col] = acc[i];
#pragma unroll
    for (int i = 0; i < 4; ++i) {
        float sv = acc[i], qv = acc[i] * acc[i];
        for (int off = 32; off; off >>= 1) { sv += __shfl_down(sv, off); qv += __shfl_down(qv, off); }
        if (col == 0) {
            atomicAdd(&stats[((size_t)t * B_ + (row0 + rg * 4 + i)) * 2 + 0], sv);
            atomicAdd(&stats[((size_t)t * B_ + (row0 + rg * 4 + i)) * 2 + 1], qv);
        }
    }
}

// ---------------- phase B step B: LN-finalize + gates + mask, in-place h/fk -------
__global__ __launch_bounds__(256) void k_stepB(float* __restrict__ Hseq,
                                               float* __restrict__ FKseq,
                                               const float* __restrict__ S1,
                                               const float* __restrict__ Y,
                                               const float* __restrict__ stats,
                                               const float* __restrict__ g1,
                                               const float* __restrict__ be1,
                                               const int* __restrict__ mask,
                                               int t) {
    int g = blockIdx.x * 256 + threadIdx.x;    // 0..B_*D_-1
    int b = g >> 10, d = g & 1023;
    size_t row = (size_t)t * B_ + b;
    float sum = stats[((size_t)t * B_ + b) * 2 + 0];
    float sq  = stats[((size_t)t * B_ + b) * 2 + 1];
    float mean = sum * (1.f / O_);
    float var  = sq * (1.f / O_) - mean * mean;
    float inv  = 1.f / (sqrtf(var + EPSf) + EPSf);
    float yd = Y[(size_t)b * O_ + d];
    float td = S1[row * O_ + d] + g1[d] * (yd - mean) * inv + be1[d];
    float fkc = fminf(fmaxf(0.2f * td + 0.5f, 0.f), 1.f);
    float xt  = Hseq[row * D_ + d];
    float h1  = (t > 0) ? Hseq[(row - B_) * D_ + d] : 0.f;
    float fk1 = (t > 0) ? FKseq[(row - B_) * D_ + d] : 0.f;
    float hpad = 0.f;
    if (d >= DIN_) {
        int e = d + 512;   // column in total for tanh branch
        float ye = Y[(size_t)b * O_ + e];
        float te = S1[row * O_ + e] + g1[e] * (ye - mean) * inv + be1[e];
        hpad = tanhf(te);
    }
    float hc  = (1.f - fkc) * xt + fkc * hpad;
    float fkp = (t + 1 < T_) ? FKseq[(row + B_) * D_ + d] : 0.f;
    float h   = fkp * h1 + (1.f - fkp) * hc;
    float fk  = fkp + (1.f - fkp) * fkc;
    bool mt = mask[b * T_ + t] != 0;
    bool mn = (t + 1 < T_) ? (mask[b * T_ + t + 1] != 0) : false;
    if (mt && !mn) fk = 0.f;
    float oh  = mt ? h : h1;
    float ofk = mt ? fk : fk1;
    Hseq[row * D_ + d]  = oh;
    FKseq[row * D_ + d] = ofk;
}

// ---------------- output: d_out[b,j] = Hseq[255][b][512+j] ----------------
__global__ __launch_bounds__(256) void k_out(const float* __restrict__ Hseq,
                                             float* __restrict__ out) {
    int g = blockIdx.x * 256 + threadIdx.x;    // 0..32767
    int b = g >> 9, j = g & 511;
    out[g] = Hseq[((size_t)255 * B_ + b) * D_ + 512 + j];
}

extern "C" void kernel_launch(void* const* d_in, const int* in_sizes, int n_in,
                              void* d_out, int out_size, void* d_ws, size_t ws_size,
                              hipStream_t stream) {
    (void)in_sizes; (void)n_in; (void)out_size;
    const float* x      = (const float*)d_in[0];
    const int*   mask   = (const int*)d_in[1];
    const float* W      = (const float*)d_in[2];
    const float* U      = (const float*)d_in[3];
    const float* bias   = (const float*)d_in[4];
    const float* gammas = (const float*)d_in[5];
    const float* betas  = (const float*)d_in[6];

    float* ws    = (float*)d_ws;
    float* Hseq  = ws;                                   // TB_*D_
    float* FKseq = Hseq  + (size_t)TB_ * D_;             // TB_*D_
    float* S1    = FKseq + (size_t)TB_ * D_;             // TB_*O_
    float* Y     = S1    + (size_t)TB_ * O_;             // B_*O_
    float* stats = Y     + (size_t)B_ * O_;              // T_*B_*2
    float* zbuf  = stats + (size_t)T_ * B_ * 2;          // B_*D_
    size_t need_bytes = ((size_t)TB_ * D_ * 2 + (size_t)TB_ * O_ +
                         (size_t)B_ * O_ + (size_t)T_ * B_ * 2 + (size_t)B_ * D_) * 4;
    if (ws_size < need_bytes) return;   // workspace too small -> fail loudly via validation

    hipMemsetAsync(FKseq, 0, sizeof(float) * (size_t)TB_ * D_, stream);
    hipMemsetAsync(zbuf,  0, sizeof(float) * (size_t)B_ * D_, stream);
    k_fill<<<TB_ * D_ / 4 / 256, 256, 0, stream>>>(x, Hseq);

    const float* g0  = gammas;       const float* g1  = gammas + O_;
    const float* be0 = betas;        const float* be1 = betas + O_;

    for (int layer = 0; layer < 4; ++layer) {
        k_gemm<<<dim3(O_ / GBN, TB_ / GBM), 256, 0, stream>>>(Hseq, W, S1, TB_, O_, D_);
        k_ln_bias<<<TB_, 256, 0, stream>>>(S1, g0, be0, bias);
        hipMemsetAsync(stats, 0, sizeof(float) * (size_t)T_ * B_ * 2, stream);
        for (int t = 0; t < T_; ++t) {
            const float* hprev = (t == 0) ? zbuf : (Hseq + (size_t)(t - 1) * B_ * D_);
            k_stepA<<<dim3(O_ / 64, B_ / 16), 256, 0, stream>>>(hprev, U, Y, stats, t);
            k_stepB<<<(B_ * D_) / 256, 256, 0, stream>>>(Hseq, FKseq, S1, Y, stats,
                                                         g1, be1, mask, t);
        }
    }
    k_out<<<(B_ * 512) / 256, 256, 0, stream>>>(Hseq, (float*)d_out);
}